// Round 3
// baseline (794.861 us; speedup 1.0000x reference)
//
#include <hip/hip_runtime.h>
#include <hip/hip_bf16.h>
#include <math.h>

// Problem constants (reference: D=300, TOPK=20, setup N=2,T=4096,h=6)
#define T      4096
#define Dm     300
#define NH     6
#define DH     50
#define NB     2
#define NBATCH 12   // NH*NB
#define KTOP   20
#define NCAND  48   // candidate count: rank20->48 margin ~0.28 >> bf16 score err ~6e-3
#define QC     8    // score kernel q-chunks (grid.z)

typedef short  bs8  __attribute__((ext_vector_type(8)));   // 8 bf16 = 4 VGPRs
typedef float  f4   __attribute__((ext_vector_type(4)));

static __device__ __forceinline__ unsigned short f2bf(float f) {
    union { float f; unsigned u; } x{f};
    unsigned r = x.u + 0x7fffu + ((x.u >> 16) & 1u);   // RNE
    return (unsigned short)(r >> 16);
}

// ---------------------------------------------------------------------------
// Kernel 1: projection (unchanged from round 2).
// Yt[b][j][t] = sum_i X[n][t][i] * W[head*DH+j][i]; b = head*NB + n.
// ---------------------------------------------------------------------------
__global__ __launch_bounds__(256) void proj_kernel(
    const float* __restrict__ Xq, const float* __restrict__ Wq_,
    const float* __restrict__ Xk, const float* __restrict__ Wk_,
    float* __restrict__ Qt, float* __restrict__ Kt)
{
    __shared__ float Xs[20][132];
    __shared__ float Ws[20][68];

    const float* X  = blockIdx.z ? Xk : Xq;
    const float* W  = blockIdx.z ? Wk_ : Wq_;
    float*       Yt = blockIdx.z ? Kt : Qt;

    const int row0 = blockIdx.x * 128;
    const int j0   = blockIdx.y * 64;
    const int tid  = threadIdx.x;
    const int tx   = tid & 15;
    const int ty   = tid >> 4;

    float acc[8][4];
#pragma unroll
    for (int r = 0; r < 8; ++r)
#pragma unroll
        for (int c = 0; c < 4; ++c) acc[r][c] = 0.f;

    for (int k0 = 0; k0 < 300; k0 += 20) {
#pragma unroll
        for (int l = 0; l < 10; ++l) {
            int idx = l * 256 + tid;
            int m = idx / 20, k = idx % 20;
            Xs[k][m] = X[(row0 + m) * 300 + k0 + k];
        }
#pragma unroll
        for (int l = 0; l < 5; ++l) {
            int idx = l * 256 + tid;
            int nn = idx / 20, k = idx % 20;
            int j = j0 + nn;
            Ws[k][nn] = (j < 300) ? W[j * 300 + k0 + k] : 0.f;
        }
        __syncthreads();
#pragma unroll
        for (int kk = 0; kk < 20; ++kk) {
            float4 xa = *(const float4*)&Xs[kk][ty * 8];
            float4 xb = *(const float4*)&Xs[kk][ty * 8 + 4];
            float4 wv = *(const float4*)&Ws[kk][tx * 4];
            float xr[8] = {xa.x, xa.y, xa.z, xa.w, xb.x, xb.y, xb.z, xb.w};
            float wc[4] = {wv.x, wv.y, wv.z, wv.w};
#pragma unroll
            for (int r = 0; r < 8; ++r)
#pragma unroll
                for (int c = 0; c < 4; ++c)
                    acc[r][c] += xr[r] * wc[c];
        }
        __syncthreads();
    }

    const int n  = row0 / T;
    const int t0 = row0 % T;
#pragma unroll
    for (int c = 0; c < 4; ++c) {
        int j = j0 + tx * 4 + c;
        if (j < 300) {
            int head = j / DH, jcol = j % DH;
            float* dst = Yt + (size_t)((head * NB + n) * DH + jcol) * T + t0 + ty * 8;
            *(float4*)dst       = make_float4(acc[0][c], acc[1][c], acc[2][c], acc[3][c]);
            *(float4*)(dst + 4) = make_float4(acc[4][c], acc[5][c], acc[6][c], acc[7][c]);
        }
    }
}

// ---------------------------------------------------------------------------
// Kernel 2: fp32 [b][50][T] -> bf16 rows [b][T][64] (d 50..63 zero-padded).
// grid (16 t-blocks, 12 b, 2 {Q,K}); reads coalesced along t, each thread
// writes its own 128 B row.
// ---------------------------------------------------------------------------
__global__ __launch_bounds__(256) void convert_kernel(
    const float* __restrict__ Qt, const float* __restrict__ Kt,
    unsigned short* __restrict__ Qb, unsigned short* __restrict__ Kb)
{
    const float* src = blockIdx.z ? Kt : Qt;
    unsigned short* dst = blockIdx.z ? Kb : Qb;
    const int b = blockIdx.y;
    const int t = blockIdx.x * 256 + threadIdx.x;

    unsigned short h[64];
#pragma unroll
    for (int d = 0; d < DH; ++d)
        h[d] = f2bf(src[((size_t)b * DH + d) * T + t]);
#pragma unroll
    for (int d = DH; d < 64; ++d) h[d] = 0;

    unsigned short* o = dst + ((size_t)b * T + t) * 64;
#pragma unroll
    for (int i = 0; i < 8; ++i)
        *(bs8*)(o + i * 8) = *(const bs8*)(h + i * 8);
}

// ---------------------------------------------------------------------------
// Kernel 3: bf16 MFMA scores + column max (approximate, for ranking only).
// grid (16 kb, 12 b, QC qc). Block: 4 waves; wave owns 64 key-cols, holds its
// 8 B-frags in registers across the whole q-loop. Q tiles (128 rows) staged in
// LDS; per q-iter per wave: 16 ds_read_b128 (A frags) + 64 MFMA -> MFMA-bound.
// pamax[qc][b][k] = partial (unscaled) max over the chunk's 512 queries.
// ---------------------------------------------------------------------------
__global__ __launch_bounds__(256) void score_mfma_kernel(
    const unsigned short* __restrict__ Qb, const unsigned short* __restrict__ Kb,
    float* __restrict__ pamax)
{
    __shared__ unsigned short Qlds[128][72];   // stride 144 B = 9 cache lines

    const int kb   = blockIdx.x;
    const int b    = blockIdx.y;
    const int qc   = blockIdx.z;
    const int tid  = threadIdx.x;
    const int wave = tid >> 6, lane = tid & 63;
    const int m16  = lane & 15, quad = lane >> 4;

    const int k0 = kb * 256 + wave * 64;

    // B fragments: B[n = lane&15][k = quad*8 + j (+32*khalf)] from key rows
    bs8 Bf[4][2];
#pragma unroll
    for (int kt = 0; kt < 4; ++kt)
#pragma unroll
        for (int h = 0; h < 2; ++h)
            Bf[kt][h] = *(const bs8*)(Kb + ((size_t)(b * T + k0 + kt * 16 + m16)) * 64
                                         + quad * 8 + h * 32);

    float cmax[4];
#pragma unroll
    for (int kt = 0; kt < 4; ++kt) cmax[kt] = -INFINITY;

    for (int it = 0; it < 4; ++it) {
        const int q0 = qc * 512 + it * 128;
        __syncthreads();
#pragma unroll
        for (int i = 0; i < 4; ++i) {
            int idx = i * 256 + tid;          // 1024 chunks of 8 shorts
            int r = idx >> 3, c = idx & 7;
            *(bs8*)&Qlds[r][c * 8] =
                *(const bs8*)(Qb + ((size_t)(b * T + q0 + r)) * 64 + c * 8);
        }
        __syncthreads();

#pragma unroll
        for (int mt = 0; mt < 8; ++mt) {
            bs8 A0 = *(const bs8*)&Qlds[mt * 16 + m16][quad * 8];
            bs8 A1 = *(const bs8*)&Qlds[mt * 16 + m16][quad * 8 + 32];
#pragma unroll
            for (int kt = 0; kt < 4; ++kt) {
                f4 acc = {0.f, 0.f, 0.f, 0.f};
                acc = __builtin_amdgcn_mfma_f32_16x16x32_bf16(A0, Bf[kt][0], acc, 0, 0, 0);
                acc = __builtin_amdgcn_mfma_f32_16x16x32_bf16(A1, Bf[kt][1], acc, 0, 0, 0);
                cmax[kt] = fmaxf(cmax[kt],
                                 fmaxf(fmaxf(acc[0], acc[1]), fmaxf(acc[2], acc[3])));
            }
        }
    }

    // cross-quad reduce (lanes sharing col = lane&15)
#pragma unroll
    for (int kt = 0; kt < 4; ++kt) {
        float v = cmax[kt];
        v = fmaxf(v, __shfl_xor(v, 16));
        v = fmaxf(v, __shfl_xor(v, 32));
        cmax[kt] = v;
    }
    if (lane < 16) {
#pragma unroll
        for (int kt = 0; kt < 4; ++kt)
            pamax[((size_t)qc * NBATCH + b) * T + k0 + kt * 16 + lane] = cmax[kt];
    }
}

// ---------------------------------------------------------------------------
// Kernel 4: per batch: reduce pamax chunks, pick top-NCAND candidate indices
// (approximate ranking; order irrelevant, distinctness guaranteed).
// ---------------------------------------------------------------------------
__global__ __launch_bounds__(256) void cand_kernel(
    const float* __restrict__ pamax, int* __restrict__ cand)
{
    __shared__ float vals[T];
    __shared__ float wredv[4];
    __shared__ int   wredi[4];

    const int b = blockIdx.x, tid = threadIdx.x;
    const int lane = tid & 63, wv = tid >> 6;

    float bv = -INFINITY; int bi = 0x7fffffff;
    for (int i = tid; i < T; i += 256) {
        float m = pamax[(size_t)b * T + i];
#pragma unroll
        for (int c = 1; c < QC; ++c)
            m = fmaxf(m, pamax[((size_t)c * NBATCH + b) * T + i]);
        vals[i] = m;
        if (m > bv) { bv = m; bi = i; }
    }
    __syncthreads();

    for (int l = 0; l < NCAND; ++l) {
        float v = bv; int i = bi;
#pragma unroll
        for (int off = 32; off > 0; off >>= 1) {
            float v2 = __shfl_down(v, off);
            int   i2 = __shfl_down(i, off);
            if (v2 > v || (v2 == v && i2 < i)) { v = v2; i = i2; }
        }
        if (lane == 0) { wredv[wv] = v; wredi[wv] = i; }
        __syncthreads();
        float sv = wredv[0]; int si = wredi[0];
#pragma unroll
        for (int w = 1; w < 4; ++w) {
            float v2 = wredv[w]; int i2 = wredi[w];
            if (v2 > sv || (v2 == sv && i2 < si)) { sv = v2; si = i2; }
        }
        if (tid == 0) cand[b * NCAND + l] = si;
        if (tid == (si & 255)) {
            vals[si] = -INFINITY;
            bv = -INFINITY; bi = 0x7fffffff;
            for (int i2 = tid; i2 < T; i2 += 256) {
                float m = vals[i2];
                if (m > bv) { bv = m; bi = i2; }
            }
        }
        __syncthreads();
    }
}

// ---------------------------------------------------------------------------
// Kernel 5: exact fp32 rescore of candidate columns.
// grid (12 b, 8 q-chunks of 512). rmax[qc][b][j] = max over chunk queries of
// dot(Q[q], K[cand_j]) in fp32 (unscaled).
// ---------------------------------------------------------------------------
__global__ __launch_bounds__(256) void rescore_kernel(
    const float* __restrict__ Qt, const float* __restrict__ Kt,
    const int* __restrict__ cand, float* __restrict__ rmax)
{
    __shared__ float Kc[NCAND][DH];
    __shared__ float red[4][NCAND];

    const int b = blockIdx.x, qch = blockIdx.y;
    const int tid = threadIdx.x;
    const int lane = tid & 63, wv = tid >> 6;

    for (int i = tid; i < NCAND * DH; i += 256) {
        int j = i / DH, d = i - j * DH;
        Kc[j][d] = Kt[((size_t)b * DH + d) * T + cand[b * NCAND + j]];
    }
    __syncthreads();

    float cm[NCAND];
#pragma unroll
    for (int j = 0; j < NCAND; ++j) cm[j] = -INFINITY;

    for (int pass = 0; pass < 2; ++pass) {
        const int q = qch * 512 + pass * 256 + tid;
        float qv[DH];
#pragma unroll
        for (int d = 0; d < DH; ++d)
            qv[d] = Qt[((size_t)b * DH + d) * T + q];
#pragma unroll
        for (int j = 0; j < NCAND; ++j) {
            float s = 0.f;
#pragma unroll
            for (int d = 0; d < DH; ++d) s = fmaf(qv[d], Kc[j][d], s);
            cm[j] = fmaxf(cm[j], s);
        }
    }

#pragma unroll
    for (int j = 0; j < NCAND; ++j) {
        float v = cm[j];
#pragma unroll
        for (int off = 32; off > 0; off >>= 1) v = fmaxf(v, __shfl_xor(v, off));
        if (lane == 0) red[wv][j] = v;
    }
    __syncthreads();
    if (tid < NCAND) {
        float v = fmaxf(fmaxf(red[0][tid], red[1][tid]),
                        fmaxf(red[2][tid], red[3][tid]));
        rmax[((size_t)qch * NBATCH + b) * NCAND + tid] = v;
    }
}

// ---------------------------------------------------------------------------
// Kernel 6: per batch (64 threads): reduce rmax, exact top-20 by value
// (index-asc tie-break), softmax, gather fp32 K rows, write output.
// ---------------------------------------------------------------------------
__global__ __launch_bounds__(64) void final_kernel(
    const float* __restrict__ rmax, const int* __restrict__ cand,
    const float* __restrict__ Kt, float* __restrict__ out)
{
    __shared__ float selval[KTOP];
    __shared__ int   selidx[KTOP];
    __shared__ float probs[KTOP];

    const int b = blockIdx.x;
    const int lane = threadIdx.x;

    float v = -INFINITY; int idx = 0x7fffffff;
    if (lane < NCAND) {
        v = rmax[(size_t)b * NCAND + lane];
#pragma unroll
        for (int c = 1; c < QC; ++c)
            v = fmaxf(v, rmax[((size_t)c * NBATCH + b) * NCAND + lane]);
        v *= 0.14142135623730951f;   // 1/sqrt(50)
        idx = cand[b * NCAND + lane];
    }

    for (int l = 0; l < KTOP; ++l) {
        float mv = v; int mi = idx;
#pragma unroll
        for (int off = 32; off > 0; off >>= 1) {
            float v2 = __shfl_xor(mv, off);
            int   i2 = __shfl_xor(mi, off);
            if (v2 > mv || (v2 == mv && i2 < mi)) { mv = v2; mi = i2; }
        }
        if (idx == mi) v = -INFINITY;   // cand indices distinct -> exactly one lane
        if (lane == 0) { selval[l] = mv; selidx[l] = mi; }
    }
    __syncthreads();

    if (lane == 0) {
        float m = selval[0];
        float s = 0.f;
        for (int l = 0; l < KTOP; ++l) { float e = expf(selval[l] - m); probs[l] = e; s += e; }
        float inv = 1.f / s;
        for (int l = 0; l < KTOP; ++l) probs[l] *= inv;
    }
    __syncthreads();

    if (lane < DH) {
        float acc = 0.f;
#pragma unroll
        for (int l = 0; l < KTOP; ++l)
            acc += probs[l] * Kt[((size_t)b * DH + lane) * T + selidx[l]];
        int head = b / NB, n = b % NB;
        out[n * Dm + head * DH + lane] = acc;
    }
}

// ---------------------------------------------------------------------------
extern "C" void kernel_launch(void* const* d_in, const int* in_sizes, int n_in,
                              void* d_out, int out_size, void* d_ws, size_t ws_size,
                              hipStream_t stream) {
    const float* querys = (const float*)d_in[0];
    const float* keys   = (const float*)d_in[1];
    const float* Wq     = (const float*)d_in[3];
    const float* Wk     = (const float*)d_in[4];

    float* out = (float*)d_out;
    float* ws  = (float*)d_ws;

    // fp32 segments
    float* Qt    = ws;                                   // 12*50*4096
    float* Kt    = Qt + (size_t)NBATCH * DH * T;         // 12*50*4096
    float* pamax = Kt + (size_t)NBATCH * DH * T;         // QC*12*4096
    float* rmax  = pamax + (size_t)QC * NBATCH * T;      // QC*12*NCAND
    // 16B-aligned tail segments
    unsigned short* Qb = (unsigned short*)(rmax + (size_t)QC * NBATCH * NCAND + 8);
    Qb = (unsigned short*)(((uintptr_t)Qb + 15) & ~(uintptr_t)15);
    unsigned short* Kb = Qb + (size_t)NBATCH * T * 64;   // 12*4096*64 bf16
    int* cand = (int*)(Kb + (size_t)NBATCH * T * 64);    // 12*NCAND
    // total ~33.9 MB

    proj_kernel   <<<dim3(64, 5, 2),      256, 0, stream>>>(querys, Wq, keys, Wk, Qt, Kt);
    convert_kernel<<<dim3(16, NBATCH, 2), 256, 0, stream>>>(Qt, Kt, Qb, Kb);
    score_mfma_kernel<<<dim3(16, NBATCH, QC), 256, 0, stream>>>(Qb, Kb, pamax);
    cand_kernel   <<<NBATCH,              256, 0, stream>>>(pamax, cand);
    rescore_kernel<<<dim3(NBATCH, QC),    256, 0, stream>>>(Qt, Kt, cand, rmax);
    final_kernel  <<<NBATCH,              64,  0, stream>>>(rmax, cand, Kt, out);
}

// Round 4
// 284.161 us; speedup vs baseline: 2.7972x; 2.7972x over previous
//
#include <hip/hip_runtime.h>
#include <hip/hip_bf16.h>
#include <math.h>

// Problem constants (reference: D=300, TOPK=20, setup N=2,T=4096,h=6)
#define T      4096
#define Dm     300
#define NH     6
#define DH     50
#define NB     2
#define NBATCH 12   // NH*NB
#define KTOP   20
#define NCAND  48   // rank20->48 margin ~0.28 >> bf16 score err ~6e-3
#define QC     8    // score kernel q-chunks (grid.z)
#define RQC    16   // rescore q-chunks (256 queries each)
#define KP     320  // proj K padded 300->320 (10 MFMA k-steps)
#define JP     304  // proj N padded 300->304 (19 j-tiles)

typedef short  bs8  __attribute__((ext_vector_type(8)));   // 8 bf16 = 4 VGPRs
typedef float  f4   __attribute__((ext_vector_type(4)));

static __device__ __forceinline__ unsigned short f2bf(float f) {
    union { float f; unsigned u; } x{f};
    unsigned r = x.u + 0x7fffu + ((x.u >> 16) & 1u);   // RNE
    return (unsigned short)(r >> 16);
}
static __device__ __forceinline__ float bf2f(unsigned short h) {
    union { unsigned u; float f; } x;
    x.u = ((unsigned)h) << 16;
    return x.f;
}

// ---------------------------------------------------------------------------
// Kernel 0: split Wq/Wk into bf16 hi/lo, padded [2][JP][KP] (zeros outside).
// ---------------------------------------------------------------------------
__global__ __launch_bounds__(256) void splitw_kernel(
    const float* __restrict__ Wq, const float* __restrict__ Wk,
    unsigned short* __restrict__ Wh, unsigned short* __restrict__ Wl)
{
    int idx = blockIdx.x * 256 + threadIdx.x;
    if (idx >= 2 * JP * KP) return;
    int z = idx / (JP * KP), rem = idx % (JP * KP);
    int row = rem / KP, k = rem % KP;
    const float* W = z ? Wk : Wq;
    float v = (row < 300 && k < 300) ? W[row * 300 + k] : 0.f;
    unsigned short h = f2bf(v);
    float r = v - bf2f(h);
    Wh[idx] = h;
    Wl[idx] = f2bf(r);
}

// ---------------------------------------------------------------------------
// Kernel 1: projection via split-bf16 MFMA (3 passes: XhWh + XhWl + XlWh).
// Error ~1.5e-5 absolute on O(1) outputs — selection-safe, output-safe.
// grid (64 m-tiles of 128 rows, 19 j-tiles of 16, 2 inputs). Block: 4 waves,
// wave handles 32 rows (2 m16-tiles) x 16 j-cols. B (W rows, hi+lo) resident
// in LDS -> barrier-free K loop. A built on the fly from fp32 X.
// Yt[b=head*NB+n][jc][t] fp32.
// ---------------------------------------------------------------------------
__global__ __launch_bounds__(256) void proj_mfma_kernel(
    const float* __restrict__ Xq, const float* __restrict__ Xk,
    const unsigned short* __restrict__ Wh, const unsigned short* __restrict__ Wl,
    float* __restrict__ Qt, float* __restrict__ Kt)
{
    __shared__ unsigned short Bh[16][KP + 8];
    __shared__ unsigned short Bl[16][KP + 8];

    const int z = blockIdx.z;
    const float* X  = z ? Xk : Xq;
    float*       Yt = z ? Kt : Qt;
    const unsigned short* WhB = Wh + (size_t)z * JP * KP;
    const unsigned short* WlB = Wl + (size_t)z * JP * KP;

    const int m0  = blockIdx.x * 128;   // row in combined [2*T] (never straddles n)
    const int j0  = blockIdx.y * 16;
    const int tid = threadIdx.x;
    const int wave = tid >> 6, lane = tid & 63;
    const int m16 = lane & 15, quad = lane >> 4;

    // stage B hi/lo: 16 rows x 320 halfwords each (40 bs8 chunks per row)
    for (int i = tid; i < 16 * 40; i += 256) {
        int row = i / 40, c = i % 40;
        *(bs8*)&Bh[row][c * 8] = *(const bs8*)(WhB + (size_t)(j0 + row) * KP + c * 8);
        *(bs8*)&Bl[row][c * 8] = *(const bs8*)(WlB + (size_t)(j0 + row) * KP + c * 8);
    }
    __syncthreads();

    f4 acc[2] = {{0.f, 0.f, 0.f, 0.f}, {0.f, 0.f, 0.f, 0.f}};
    const int rowbase = m0 + wave * 32;

    for (int ks = 0; ks < 10; ++ks) {
        bs8 Ah[2], Al[2];
#pragma unroll
        for (int mt = 0; mt < 2; ++mt) {
            const int row = rowbase + mt * 16 + m16;
            const float* src = X + (size_t)row * 300 + ks * 32 + quad * 8;
            float f[8];
            if (ks < 9) {
                float4 a = *(const float4*)src;
                float4 c = *(const float4*)(src + 4);
                f[0] = a.x; f[1] = a.y; f[2] = a.z; f[3] = a.w;
                f[4] = c.x; f[5] = c.y; f[6] = c.z; f[7] = c.w;
            } else {
                const float* rowp = X + (size_t)row * 300;
#pragma unroll
                for (int e = 0; e < 8; ++e) {
                    int k = 288 + quad * 8 + e;
                    float v = rowp[k < 300 ? k : 299];   // always in-bounds
                    f[e] = (k < 300) ? v : 0.f;
                }
            }
#pragma unroll
            for (int e = 0; e < 8; ++e) {
                unsigned short h = f2bf(f[e]);
                float r = f[e] - bf2f(h);
                Ah[mt][e] = (short)h;
                Al[mt][e] = (short)f2bf(r);
            }
        }
        bs8 Bfh = *(const bs8*)&Bh[m16][ks * 32 + quad * 8];
        bs8 Bfl = *(const bs8*)&Bl[m16][ks * 32 + quad * 8];
#pragma unroll
        for (int mt = 0; mt < 2; ++mt) {
            acc[mt] = __builtin_amdgcn_mfma_f32_16x16x32_bf16(Ah[mt], Bfh, acc[mt], 0, 0, 0);
            acc[mt] = __builtin_amdgcn_mfma_f32_16x16x32_bf16(Al[mt], Bfh, acc[mt], 0, 0, 0);
            acc[mt] = __builtin_amdgcn_mfma_f32_16x16x32_bf16(Ah[mt], Bfl, acc[mt], 0, 0, 0);
        }
    }

    // C layout: col j = lane&15, row t = quad*4 + reg  ->  float4 along t
    const int j = j0 + m16;
    if (j < 300) {
        const int head = j / DH, jc = j % DH;
        const int n    = m0 >> 12;           // /T
        const int tloc = (m0 & (T - 1)) + wave * 32;
        float* base = Yt + ((size_t)(head * NB + n) * DH + jc) * T;
#pragma unroll
        for (int mt = 0; mt < 2; ++mt) {
            int t = tloc + mt * 16 + quad * 4;
            *(float4*)(base + t) = make_float4(acc[mt][0], acc[mt][1], acc[mt][2], acc[mt][3]);
        }
    }
}

// ---------------------------------------------------------------------------
// Kernel 2: fp32 [b][50][T] -> bf16 rows [b][T][64] (d 50..63 zero-padded).
// ---------------------------------------------------------------------------
__global__ __launch_bounds__(256) void convert_kernel(
    const float* __restrict__ Qt, const float* __restrict__ Kt,
    unsigned short* __restrict__ Qb, unsigned short* __restrict__ Kb)
{
    const float* src = blockIdx.z ? Kt : Qt;
    unsigned short* dst = blockIdx.z ? Kb : Qb;
    const int b = blockIdx.y;
    const int t = blockIdx.x * 256 + threadIdx.x;

    unsigned short h[64];
#pragma unroll
    for (int d = 0; d < DH; ++d)
        h[d] = f2bf(src[((size_t)b * DH + d) * T + t]);
#pragma unroll
    for (int d = DH; d < 64; ++d) h[d] = 0;

    unsigned short* o = dst + ((size_t)b * T + t) * 64;
#pragma unroll
    for (int i = 0; i < 8; ++i)
        *(bs8*)(o + i * 8) = *(const bs8*)(h + i * 8);
}

// ---------------------------------------------------------------------------
// Kernel 3: bf16 MFMA scores + column max (ranking only).
// ---------------------------------------------------------------------------
__global__ __launch_bounds__(256) void score_mfma_kernel(
    const unsigned short* __restrict__ Qb, const unsigned short* __restrict__ Kb,
    float* __restrict__ pamax)
{
    __shared__ unsigned short Qlds[128][72];

    const int kb   = blockIdx.x;
    const int b    = blockIdx.y;
    const int qc   = blockIdx.z;
    const int tid  = threadIdx.x;
    const int wave = tid >> 6, lane = tid & 63;
    const int m16  = lane & 15, quad = lane >> 4;

    const int k0 = kb * 256 + wave * 64;

    bs8 Bf[4][2];
#pragma unroll
    for (int kt = 0; kt < 4; ++kt)
#pragma unroll
        for (int h = 0; h < 2; ++h)
            Bf[kt][h] = *(const bs8*)(Kb + ((size_t)(b * T + k0 + kt * 16 + m16)) * 64
                                         + quad * 8 + h * 32);

    float cmax[4];
#pragma unroll
    for (int kt = 0; kt < 4; ++kt) cmax[kt] = -INFINITY;

    for (int it = 0; it < 4; ++it) {
        const int q0 = qc * 512 + it * 128;
        __syncthreads();
#pragma unroll
        for (int i = 0; i < 4; ++i) {
            int idx = i * 256 + tid;
            int r = idx >> 3, c = idx & 7;
            *(bs8*)&Qlds[r][c * 8] =
                *(const bs8*)(Qb + ((size_t)(b * T + q0 + r)) * 64 + c * 8);
        }
        __syncthreads();

#pragma unroll
        for (int mt = 0; mt < 8; ++mt) {
            bs8 A0 = *(const bs8*)&Qlds[mt * 16 + m16][quad * 8];
            bs8 A1 = *(const bs8*)&Qlds[mt * 16 + m16][quad * 8 + 32];
#pragma unroll
            for (int kt = 0; kt < 4; ++kt) {
                f4 acc = {0.f, 0.f, 0.f, 0.f};
                acc = __builtin_amdgcn_mfma_f32_16x16x32_bf16(A0, Bf[kt][0], acc, 0, 0, 0);
                acc = __builtin_amdgcn_mfma_f32_16x16x32_bf16(A1, Bf[kt][1], acc, 0, 0, 0);
                cmax[kt] = fmaxf(cmax[kt],
                                 fmaxf(fmaxf(acc[0], acc[1]), fmaxf(acc[2], acc[3])));
            }
        }
    }

#pragma unroll
    for (int kt = 0; kt < 4; ++kt) {
        float v = cmax[kt];
        v = fmaxf(v, __shfl_xor(v, 16));
        v = fmaxf(v, __shfl_xor(v, 32));
        cmax[kt] = v;
    }
    if (lane < 16) {
#pragma unroll
        for (int kt = 0; kt < 4; ++kt)
            pamax[((size_t)qc * NBATCH + b) * T + k0 + kt * 16 + lane] = cmax[kt];
    }
}

// ---------------------------------------------------------------------------
// Kernel 4: per batch: reduce pamax chunks, pick top-NCAND candidates.
// ---------------------------------------------------------------------------
__global__ __launch_bounds__(256) void cand_kernel(
    const float* __restrict__ pamax, int* __restrict__ cand)
{
    __shared__ float vals[T];
    __shared__ float wredv[4];
    __shared__ int   wredi[4];

    const int b = blockIdx.x, tid = threadIdx.x;
    const int lane = tid & 63, wv = tid >> 6;

    float bv = -INFINITY; int bi = 0x7fffffff;
    for (int i = tid; i < T; i += 256) {
        float m = pamax[(size_t)b * T + i];
#pragma unroll
        for (int c = 1; c < QC; ++c)
            m = fmaxf(m, pamax[((size_t)c * NBATCH + b) * T + i]);
        vals[i] = m;
        if (m > bv) { bv = m; bi = i; }
    }
    __syncthreads();

    for (int l = 0; l < NCAND; ++l) {
        float v = bv; int i = bi;
#pragma unroll
        for (int off = 32; off > 0; off >>= 1) {
            float v2 = __shfl_down(v, off);
            int   i2 = __shfl_down(i, off);
            if (v2 > v || (v2 == v && i2 < i)) { v = v2; i = i2; }
        }
        if (lane == 0) { wredv[wv] = v; wredi[wv] = i; }
        __syncthreads();
        float sv = wredv[0]; int si = wredi[0];
#pragma unroll
        for (int w = 1; w < 4; ++w) {
            float v2 = wredv[w]; int i2 = wredi[w];
            if (v2 > sv || (v2 == sv && i2 < si)) { sv = v2; si = i2; }
        }
        if (tid == 0) cand[b * NCAND + l] = si;
        if (tid == (si & 255)) {
            vals[si] = -INFINITY;
            bv = -INFINITY; bi = 0x7fffffff;
            for (int i2 = tid; i2 < T; i2 += 256) {
                float m = vals[i2];
                if (m > bv) { bv = m; bi = i2; }
            }
        }
        __syncthreads();
    }
}

// ---------------------------------------------------------------------------
// Kernel 5: exact fp32 rescore (REWRITTEN: 1 query/thread, candidate groups
// of 8 -> no spills). grid (12 b, RQC=16 chunks of 256 queries).
// rmax[qch][b][j] = max over chunk queries of dot(Q[q], K[cand_j]).
// ---------------------------------------------------------------------------
__global__ __launch_bounds__(256) void rescore_kernel(
    const float* __restrict__ Qt, const float* __restrict__ Kt,
    const int* __restrict__ cand, float* __restrict__ rmax)
{
    __shared__ float KcT[DH][NCAND];   // transposed: row d, col j
    __shared__ float red[4][NCAND];

    const int b = blockIdx.x, qch = blockIdx.y;
    const int tid = threadIdx.x;
    const int lane = tid & 63, wv = tid >> 6;

    for (int i = tid; i < NCAND * DH; i += 256) {
        int j = i / DH, d = i - j * DH;
        KcT[d][j] = Kt[((size_t)b * DH + d) * T + cand[b * NCAND + j]];
    }
    __syncthreads();

    const int q = qch * 256 + tid;
    float qv[DH];
#pragma unroll
    for (int d = 0; d < DH; ++d)
        qv[d] = Qt[((size_t)b * DH + d) * T + q];

    for (int g = 0; g < NCAND / 8; ++g) {
        float cm[8];
#pragma unroll
        for (int j = 0; j < 8; ++j) cm[j] = 0.f;
#pragma unroll
        for (int d = 0; d < DH; ++d) {
            float4 ka = *(const float4*)&KcT[d][g * 8];
            float4 kb = *(const float4*)&KcT[d][g * 8 + 4];
            cm[0] = fmaf(qv[d], ka.x, cm[0]);
            cm[1] = fmaf(qv[d], ka.y, cm[1]);
            cm[2] = fmaf(qv[d], ka.z, cm[2]);
            cm[3] = fmaf(qv[d], ka.w, cm[3]);
            cm[4] = fmaf(qv[d], kb.x, cm[4]);
            cm[5] = fmaf(qv[d], kb.y, cm[5]);
            cm[6] = fmaf(qv[d], kb.z, cm[6]);
            cm[7] = fmaf(qv[d], kb.w, cm[7]);
        }
#pragma unroll
        for (int j = 0; j < 8; ++j) {
            float v = cm[j];
#pragma unroll
            for (int off = 32; off > 0; off >>= 1)
                v = fmaxf(v, __shfl_xor(v, off));
            if (lane == 0) red[wv][g * 8 + j] = v;
        }
    }
    __syncthreads();

    if (tid < NCAND) {
        float v = fmaxf(fmaxf(red[0][tid], red[1][tid]),
                        fmaxf(red[2][tid], red[3][tid]));
        rmax[((size_t)qch * NBATCH + b) * NCAND + tid] = v;
    }
}

// ---------------------------------------------------------------------------
// Kernel 6: per batch (64 threads): reduce rmax, exact top-20, softmax,
// gather fp32 K rows, write output.
// ---------------------------------------------------------------------------
__global__ __launch_bounds__(64) void final_kernel(
    const float* __restrict__ rmax, const int* __restrict__ cand,
    const float* __restrict__ Kt, float* __restrict__ out)
{
    __shared__ float selval[KTOP];
    __shared__ int   selidx[KTOP];
    __shared__ float probs[KTOP];

    const int b = blockIdx.x;
    const int lane = threadIdx.x;

    float v = -INFINITY; int idx = 0x7fffffff;
    if (lane < NCAND) {
        v = rmax[(size_t)b * NCAND + lane];
#pragma unroll
        for (int c = 1; c < RQC; ++c)
            v = fmaxf(v, rmax[((size_t)c * NBATCH + b) * NCAND + lane]);
        v *= 0.14142135623730951f;   // 1/sqrt(50)
        idx = cand[b * NCAND + lane];
    }

    for (int l = 0; l < KTOP; ++l) {
        float mv = v; int mi = idx;
#pragma unroll
        for (int off = 32; off > 0; off >>= 1) {
            float v2 = __shfl_xor(mv, off);
            int   i2 = __shfl_xor(mi, off);
            if (v2 > mv || (v2 == mv && i2 < mi)) { mv = v2; mi = i2; }
        }
        if (idx == mi) v = -INFINITY;   // cand indices distinct
        if (lane == 0) { selval[l] = mv; selidx[l] = mi; }
    }
    __syncthreads();

    if (lane == 0) {
        float m = selval[0];
        float s = 0.f;
        for (int l = 0; l < KTOP; ++l) { float e = expf(selval[l] - m); probs[l] = e; s += e; }
        float inv = 1.f / s;
        for (int l = 0; l < KTOP; ++l) probs[l] *= inv;
    }
    __syncthreads();

    if (lane < DH) {
        float acc = 0.f;
#pragma unroll
        for (int l = 0; l < KTOP; ++l)
            acc += probs[l] * Kt[((size_t)b * DH + lane) * T + selidx[l]];
        int head = b / NB, n = b % NB;
        out[n * Dm + head * DH + lane] = acc;
    }
}

// ---------------------------------------------------------------------------
extern "C" void kernel_launch(void* const* d_in, const int* in_sizes, int n_in,
                              void* d_out, int out_size, void* d_ws, size_t ws_size,
                              hipStream_t stream) {
    const float* querys = (const float*)d_in[0];
    const float* keys   = (const float*)d_in[1];
    const float* Wq     = (const float*)d_in[3];
    const float* Wk     = (const float*)d_in[4];

    float* out = (float*)d_out;
    float* ws  = (float*)d_ws;

    float* Qt    = ws;                                   // 12*50*4096 f
    float* Kt    = Qt + (size_t)NBATCH * DH * T;         // 12*50*4096 f
    float* pamax = Kt + (size_t)NBATCH * DH * T;         // QC*12*4096 f
    float* rmax  = pamax + (size_t)QC * NBATCH * T;      // RQC*12*NCAND f
    unsigned short* Qb = (unsigned short*)(rmax + (size_t)RQC * NBATCH * NCAND + 8);
    Qb = (unsigned short*)(((uintptr_t)Qb + 15) & ~(uintptr_t)15);
    unsigned short* Kb  = Qb  + (size_t)NBATCH * T * 64; // 12*4096*64 ush
    unsigned short* Whs = Kb  + (size_t)NBATCH * T * 64; // 2*304*320 ush
    unsigned short* Wls = Whs + (size_t)2 * JP * KP;
    int* cand = (int*)(Wls + (size_t)2 * JP * KP);       // 12*NCAND
    // total ~34.7 MB

    splitw_kernel   <<<(2 * JP * KP + 255) / 256, 256, 0, stream>>>(Wq, Wk, Whs, Wls);
    proj_mfma_kernel<<<dim3(64, JP / 16, 2), 256, 0, stream>>>(querys, keys, Whs, Wls, Qt, Kt);
    convert_kernel  <<<dim3(16, NBATCH, 2), 256, 0, stream>>>(Qt, Kt, Qb, Kb);
    score_mfma_kernel<<<dim3(16, NBATCH, QC), 256, 0, stream>>>(Qb, Kb, pamax);
    cand_kernel     <<<NBATCH, 256, 0, stream>>>(pamax, cand);
    rescore_kernel  <<<dim3(NBATCH, RQC), 256, 0, stream>>>(Qt, Kt, cand, rmax);
    final_kernel    <<<NBATCH, 64, 0, stream>>>(rmax, cand, Kt, out);
}

// Round 5
// 242.013 us; speedup vs baseline: 3.2844x; 1.1742x over previous
//
#include <hip/hip_runtime.h>
#include <hip/hip_bf16.h>
#include <math.h>

// Problem constants (reference: D=300, TOPK=20, setup N=2,T=4096,h=6)
#define T      4096
#define Dm     300
#define NH     6
#define DH     50
#define NB     2
#define NBATCH 12   // NH*NB
#define KTOP   20
#define NCAND  48   // rank20->48 margin ~0.28 >> bf16 score err ~6e-3
#define QC     8    // score kernel q-chunks (grid.z)
#define RQC    16   // rescore q-chunks (256 queries each)
#define KP     320  // proj K padded 300->320 (10 MFMA k-steps)
#define JP     304  // proj N padded 300->304 (19 j-tiles)
#define NBINS  4096 // cand radix-select histogram bins (top 12 key bits)
#define BMAX   1024 // boundary-bin list cap

typedef short  bs8  __attribute__((ext_vector_type(8)));   // 8 bf16 = 4 VGPRs
typedef float  f4   __attribute__((ext_vector_type(4)));

static __device__ __forceinline__ unsigned short f2bf(float f) {
    union { float f; unsigned u; } x{f};
    unsigned r = x.u + 0x7fffu + ((x.u >> 16) & 1u);   // RNE
    return (unsigned short)(r >> 16);
}
static __device__ __forceinline__ float bf2f(unsigned short h) {
    union { unsigned u; float f; } x;
    x.u = ((unsigned)h) << 16;
    return x.f;
}
// order-preserving float -> uint key (a>b  <=>  fkey(a)>fkey(b))
static __device__ __forceinline__ unsigned fkey(float f) {
    unsigned u = __float_as_uint(f);
    return (u & 0x80000000u) ? ~u : (u | 0x80000000u);
}

// ---------------------------------------------------------------------------
// Kernel 0: split Wq/Wk into bf16 hi/lo, padded [2][JP][KP] (zeros outside).
// ---------------------------------------------------------------------------
__global__ __launch_bounds__(256) void splitw_kernel(
    const float* __restrict__ Wq, const float* __restrict__ Wk,
    unsigned short* __restrict__ Wh, unsigned short* __restrict__ Wl)
{
    int idx = blockIdx.x * 256 + threadIdx.x;
    if (idx >= 2 * JP * KP) return;
    int z = idx / (JP * KP), rem = idx % (JP * KP);
    int row = rem / KP, k = rem % KP;
    const float* W = z ? Wk : Wq;
    float v = (row < 300 && k < 300) ? W[row * 300 + k] : 0.f;
    unsigned short h = f2bf(v);
    float r = v - bf2f(h);
    Wh[idx] = h;
    Wl[idx] = f2bf(r);
}

// ---------------------------------------------------------------------------
// Kernel 1: projection via split-bf16 MFMA (3 passes: XhWh + XhWl + XlWh).
// ---------------------------------------------------------------------------
__global__ __launch_bounds__(256) void proj_mfma_kernel(
    const float* __restrict__ Xq, const float* __restrict__ Xk,
    const unsigned short* __restrict__ Wh, const unsigned short* __restrict__ Wl,
    float* __restrict__ Qt, float* __restrict__ Kt)
{
    __shared__ unsigned short Bh[16][KP + 8];
    __shared__ unsigned short Bl[16][KP + 8];

    const int z = blockIdx.z;
    const float* X  = z ? Xk : Xq;
    float*       Yt = z ? Kt : Qt;
    const unsigned short* WhB = Wh + (size_t)z * JP * KP;
    const unsigned short* WlB = Wl + (size_t)z * JP * KP;

    const int m0  = blockIdx.x * 128;
    const int j0  = blockIdx.y * 16;
    const int tid = threadIdx.x;
    const int wave = tid >> 6, lane = tid & 63;
    const int m16 = lane & 15, quad = lane >> 4;

    for (int i = tid; i < 16 * 40; i += 256) {
        int row = i / 40, c = i % 40;
        *(bs8*)&Bh[row][c * 8] = *(const bs8*)(WhB + (size_t)(j0 + row) * KP + c * 8);
        *(bs8*)&Bl[row][c * 8] = *(const bs8*)(WlB + (size_t)(j0 + row) * KP + c * 8);
    }
    __syncthreads();

    f4 acc[2] = {{0.f, 0.f, 0.f, 0.f}, {0.f, 0.f, 0.f, 0.f}};
    const int rowbase = m0 + wave * 32;

    for (int ks = 0; ks < 10; ++ks) {
        bs8 Ah[2], Al[2];
#pragma unroll
        for (int mt = 0; mt < 2; ++mt) {
            const int row = rowbase + mt * 16 + m16;
            const float* src = X + (size_t)row * 300 + ks * 32 + quad * 8;
            float f[8];
            if (ks < 9) {
                float4 a = *(const float4*)src;
                float4 c = *(const float4*)(src + 4);
                f[0] = a.x; f[1] = a.y; f[2] = a.z; f[3] = a.w;
                f[4] = c.x; f[5] = c.y; f[6] = c.z; f[7] = c.w;
            } else {
                const float* rowp = X + (size_t)row * 300;
#pragma unroll
                for (int e = 0; e < 8; ++e) {
                    int k = 288 + quad * 8 + e;
                    float v = rowp[k < 300 ? k : 299];
                    f[e] = (k < 300) ? v : 0.f;
                }
            }
#pragma unroll
            for (int e = 0; e < 8; ++e) {
                unsigned short h = f2bf(f[e]);
                float r = f[e] - bf2f(h);
                Ah[mt][e] = (short)h;
                Al[mt][e] = (short)f2bf(r);
            }
        }
        bs8 Bfh = *(const bs8*)&Bh[m16][ks * 32 + quad * 8];
        bs8 Bfl = *(const bs8*)&Bl[m16][ks * 32 + quad * 8];
#pragma unroll
        for (int mt = 0; mt < 2; ++mt) {
            acc[mt] = __builtin_amdgcn_mfma_f32_16x16x32_bf16(Ah[mt], Bfh, acc[mt], 0, 0, 0);
            acc[mt] = __builtin_amdgcn_mfma_f32_16x16x32_bf16(Al[mt], Bfh, acc[mt], 0, 0, 0);
            acc[mt] = __builtin_amdgcn_mfma_f32_16x16x32_bf16(Ah[mt], Bfl, acc[mt], 0, 0, 0);
        }
    }

    const int j = j0 + m16;
    if (j < 300) {
        const int head = j / DH, jc = j % DH;
        const int n    = m0 >> 12;
        const int tloc = (m0 & (T - 1)) + wave * 32;
        float* base = Yt + ((size_t)(head * NB + n) * DH + jc) * T;
#pragma unroll
        for (int mt = 0; mt < 2; ++mt) {
            int t = tloc + mt * 16 + quad * 4;
            *(float4*)(base + t) = make_float4(acc[mt][0], acc[mt][1], acc[mt][2], acc[mt][3]);
        }
    }
}

// ---------------------------------------------------------------------------
// Kernel 2: fp32 [b][50][T] -> bf16 rows [b][T][64] (d 50..63 zero-padded).
// ---------------------------------------------------------------------------
__global__ __launch_bounds__(256) void convert_kernel(
    const float* __restrict__ Qt, const float* __restrict__ Kt,
    unsigned short* __restrict__ Qb, unsigned short* __restrict__ Kb)
{
    const float* src = blockIdx.z ? Kt : Qt;
    unsigned short* dst = blockIdx.z ? Kb : Qb;
    const int b = blockIdx.y;
    const int t = blockIdx.x * 256 + threadIdx.x;

    unsigned short h[64];
#pragma unroll
    for (int d = 0; d < DH; ++d)
        h[d] = f2bf(src[((size_t)b * DH + d) * T + t]);
#pragma unroll
    for (int d = DH; d < 64; ++d) h[d] = 0;

    unsigned short* o = dst + ((size_t)b * T + t) * 64;
#pragma unroll
    for (int i = 0; i < 8; ++i)
        *(bs8*)(o + i * 8) = *(const bs8*)(h + i * 8);
}

// ---------------------------------------------------------------------------
// Kernel 3: bf16 MFMA scores + column max (ranking only).
// ---------------------------------------------------------------------------
__global__ __launch_bounds__(256) void score_mfma_kernel(
    const unsigned short* __restrict__ Qb, const unsigned short* __restrict__ Kb,
    float* __restrict__ pamax)
{
    __shared__ unsigned short Qlds[128][72];

    const int kb   = blockIdx.x;
    const int b    = blockIdx.y;
    const int qc   = blockIdx.z;
    const int tid  = threadIdx.x;
    const int wave = tid >> 6, lane = tid & 63;
    const int m16  = lane & 15, quad = lane >> 4;

    const int k0 = kb * 256 + wave * 64;

    bs8 Bf[4][2];
#pragma unroll
    for (int kt = 0; kt < 4; ++kt)
#pragma unroll
        for (int h = 0; h < 2; ++h)
            Bf[kt][h] = *(const bs8*)(Kb + ((size_t)(b * T + k0 + kt * 16 + m16)) * 64
                                         + quad * 8 + h * 32);

    float cmax[4];
#pragma unroll
    for (int kt = 0; kt < 4; ++kt) cmax[kt] = -INFINITY;

    for (int it = 0; it < 4; ++it) {
        const int q0 = qc * 512 + it * 128;
        __syncthreads();
#pragma unroll
        for (int i = 0; i < 4; ++i) {
            int idx = i * 256 + tid;
            int r = idx >> 3, c = idx & 7;
            *(bs8*)&Qlds[r][c * 8] =
                *(const bs8*)(Qb + ((size_t)(b * T + q0 + r)) * 64 + c * 8);
        }
        __syncthreads();

#pragma unroll
        for (int mt = 0; mt < 8; ++mt) {
            bs8 A0 = *(const bs8*)&Qlds[mt * 16 + m16][quad * 8];
            bs8 A1 = *(const bs8*)&Qlds[mt * 16 + m16][quad * 8 + 32];
#pragma unroll
            for (int kt = 0; kt < 4; ++kt) {
                f4 acc = {0.f, 0.f, 0.f, 0.f};
                acc = __builtin_amdgcn_mfma_f32_16x16x32_bf16(A0, Bf[kt][0], acc, 0, 0, 0);
                acc = __builtin_amdgcn_mfma_f32_16x16x32_bf16(A1, Bf[kt][1], acc, 0, 0, 0);
                cmax[kt] = fmaxf(cmax[kt],
                                 fmaxf(fmaxf(acc[0], acc[1]), fmaxf(acc[2], acc[3])));
            }
        }
    }

#pragma unroll
    for (int kt = 0; kt < 4; ++kt) {
        float v = cmax[kt];
        v = fmaxf(v, __shfl_xor(v, 16));
        v = fmaxf(v, __shfl_xor(v, 32));
        cmax[kt] = v;
    }
    if (lane < 16) {
#pragma unroll
        for (int kt = 0; kt < 4; ++kt)
            pamax[((size_t)qc * NBATCH + b) * T + k0 + kt * 16 + lane] = cmax[kt];
    }
}

// ---------------------------------------------------------------------------
// Kernel 4 (REWRITTEN): per batch, radix-select top-NCAND candidate set.
// (1) chunk-reduce pamax -> vals + 4096-bin histogram of order-preserving key
// (2) parallel suffix-sum locates threshold bin B (desc cumulative crosses 48)
// (3) compaction: bins > B -> candidates (set semantics, order irrelevant);
//     boundary bin B resolved exactly by short wave argmax (smallest-t ties).
// ---------------------------------------------------------------------------
__global__ __launch_bounds__(256) void cand_kernel(
    const float* __restrict__ pamax, int* __restrict__ cand)
{
    __shared__ float vals[T];          // 16 KB
    __shared__ int   hist[NBINS];      // 16 KB
    __shared__ int   part[256];        // suffix partials per thread-group
    __shared__ int   bidx[BMAX];       // boundary-bin t indices
    __shared__ float bval[BMAX];       // boundary-bin values
    __shared__ int   sh_B, sh_c1, sh_nout, sh_nb;

    const int b = blockIdx.x, tid = threadIdx.x;

    for (int i = tid; i < NBINS; i += 256) hist[i] = 0;
    if (tid == 0) { sh_nout = 0; sh_nb = 0; }
    __syncthreads();

    // (1) reduce QC chunks, store vals, build histogram
    for (int i = tid; i < T; i += 256) {
        float m = pamax[(size_t)b * T + i];
#pragma unroll
        for (int c = 1; c < QC; ++c)
            m = fmaxf(m, pamax[((size_t)c * NBATCH + b) * T + i]);
        vals[i] = m;
        atomicAdd(&hist[fkey(m) >> 20], 1);
    }
    __syncthreads();

    // (2) suffix sums: part[t] = count of keys in bins >= t*16
    {
        int s = 0;
#pragma unroll
        for (int k = 0; k < 16; ++k) s += hist[tid * 16 + k];
        part[tid] = s;
        __syncthreads();
        for (int off = 1; off < 256; off <<= 1) {
            int v = (tid + off < 256) ? part[tid + off] : 0;
            __syncthreads();
            part[tid] += v;
            __syncthreads();
        }
        // find threshold bin B within this thread's 16 bins
        int run = (tid < 255) ? part[tid + 1] : 0;   // count in bins >= (tid+1)*16
        for (int k = 15; k >= 0; --k) {
            int bin = tid * 16 + k;
            int c = hist[bin];
            if (run < NCAND && run + c >= NCAND) { sh_B = bin; sh_c1 = run; }
            run += c;
        }
    }
    __syncthreads();

    const int B = sh_B;

    // (3) compaction
    for (int i = tid; i < T; i += 256) {
        int kb = (int)(fkey(vals[i]) >> 20);
        if (kb > B) {
            int p = atomicAdd(&sh_nout, 1);
            cand[b * NCAND + p] = i;
        } else if (kb == B) {
            int p = atomicAdd(&sh_nb, 1);
            if (p < BMAX) { bidx[p] = i; bval[p] = vals[i]; }
        }
    }
    __syncthreads();

    // boundary bin: exact top-(NCAND - c1) by value (smallest-t tie-break)
    const int c1   = sh_nout;            // == sh_c1, strictly-above count (<48)
    const int need = NCAND - c1;
    const int nb   = (sh_nb < BMAX) ? sh_nb : BMAX;
    if (tid < 64) {
        for (int l = 0; l < need; ++l) {
            float mv = -INFINITY; int mp = -1, mt = 0x7fffffff;
            for (int j = tid; j < nb; j += 64) {
                float v = bval[j]; int t = bidx[j];
                if (v > mv || (v == mv && t < mt)) { mv = v; mp = j; mt = t; }
            }
#pragma unroll
            for (int off = 32; off > 0; off >>= 1) {
                float v2 = __shfl_xor(mv, off);
                int   p2 = __shfl_xor(mp, off);
                int   t2 = __shfl_xor(mt, off);
                if (v2 > mv || (v2 == mv && t2 < mt)) { mv = v2; mp = p2; mt = t2; }
            }
            if (tid == 0)
                cand[b * NCAND + c1 + l] = (mp >= 0) ? bidx[mp] : l;  // filler unreachable
            if (mp >= 0 && tid == (mp & 63)) bval[mp] = -INFINITY;
        }
    }
}

// ---------------------------------------------------------------------------
// Kernel 5: exact fp32 rescore (1 query/thread, candidate groups of 8).
// ---------------------------------------------------------------------------
__global__ __launch_bounds__(256) void rescore_kernel(
    const float* __restrict__ Qt, const float* __restrict__ Kt,
    const int* __restrict__ cand, float* __restrict__ rmax)
{
    __shared__ float KcT[DH][NCAND];
    __shared__ float red[4][NCAND];

    const int b = blockIdx.x, qch = blockIdx.y;
    const int tid = threadIdx.x;
    const int lane = tid & 63, wv = tid >> 6;

    for (int i = tid; i < NCAND * DH; i += 256) {
        int j = i / DH, d = i - j * DH;
        KcT[d][j] = Kt[((size_t)b * DH + d) * T + cand[b * NCAND + j]];
    }
    __syncthreads();

    const int q = qch * 256 + tid;
    float qv[DH];
#pragma unroll
    for (int d = 0; d < DH; ++d)
        qv[d] = Qt[((size_t)b * DH + d) * T + q];

    for (int g = 0; g < NCAND / 8; ++g) {
        float cm[8];
#pragma unroll
        for (int j = 0; j < 8; ++j) cm[j] = 0.f;
#pragma unroll
        for (int d = 0; d < DH; ++d) {
            float4 ka = *(const float4*)&KcT[d][g * 8];
            float4 kb = *(const float4*)&KcT[d][g * 8 + 4];
            cm[0] = fmaf(qv[d], ka.x, cm[0]);
            cm[1] = fmaf(qv[d], ka.y, cm[1]);
            cm[2] = fmaf(qv[d], ka.z, cm[2]);
            cm[3] = fmaf(qv[d], ka.w, cm[3]);
            cm[4] = fmaf(qv[d], kb.x, cm[4]);
            cm[5] = fmaf(qv[d], kb.y, cm[5]);
            cm[6] = fmaf(qv[d], kb.z, cm[6]);
            cm[7] = fmaf(qv[d], kb.w, cm[7]);
        }
#pragma unroll
        for (int j = 0; j < 8; ++j) {
            float v = cm[j];
#pragma unroll
            for (int off = 32; off > 0; off >>= 1)
                v = fmaxf(v, __shfl_xor(v, off));
            if (lane == 0) red[wv][g * 8 + j] = v;
        }
    }
    __syncthreads();

    if (tid < NCAND) {
        float v = fmaxf(fmaxf(red[0][tid], red[1][tid]),
                        fmaxf(red[2][tid], red[3][tid]));
        rmax[((size_t)qch * NBATCH + b) * NCAND + tid] = v;
    }
}

// ---------------------------------------------------------------------------
// Kernel 6: per batch (64 threads): reduce rmax, exact top-20, softmax,
// gather fp32 K rows, write output.
// ---------------------------------------------------------------------------
__global__ __launch_bounds__(64) void final_kernel(
    const float* __restrict__ rmax, const int* __restrict__ cand,
    const float* __restrict__ Kt, float* __restrict__ out)
{
    __shared__ float selval[KTOP];
    __shared__ int   selidx[KTOP];
    __shared__ float probs[KTOP];

    const int b = blockIdx.x;
    const int lane = threadIdx.x;

    float v = -INFINITY; int idx = 0x7fffffff;
    if (lane < NCAND) {
        v = rmax[(size_t)b * NCAND + lane];
#pragma unroll
        for (int c = 1; c < RQC; ++c)
            v = fmaxf(v, rmax[((size_t)c * NBATCH + b) * NCAND + lane]);
        v *= 0.14142135623730951f;   // 1/sqrt(50)
        idx = cand[b * NCAND + lane];
    }

    for (int l = 0; l < KTOP; ++l) {
        float mv = v; int mi = idx;
#pragma unroll
        for (int off = 32; off > 0; off >>= 1) {
            float v2 = __shfl_xor(mv, off);
            int   i2 = __shfl_xor(mi, off);
            if (v2 > mv || (v2 == mv && i2 < mi)) { mv = v2; mi = i2; }
        }
        if (idx == mi) v = -INFINITY;   // cand indices distinct
        if (lane == 0) { selval[l] = mv; selidx[l] = mi; }
    }
    __syncthreads();

    if (lane == 0) {
        float m = selval[0];
        float s = 0.f;
        for (int l = 0; l < KTOP; ++l) { float e = expf(selval[l] - m); probs[l] = e; s += e; }
        float inv = 1.f / s;
        for (int l = 0; l < KTOP; ++l) probs[l] *= inv;
    }
    __syncthreads();

    if (lane < DH) {
        float acc = 0.f;
#pragma unroll
        for (int l = 0; l < KTOP; ++l)
            acc += probs[l] * Kt[((size_t)b * DH + lane) * T + selidx[l]];
        int head = b / NB, n = b % NB;
        out[n * Dm + head * DH + lane] = acc;
    }
}

// ---------------------------------------------------------------------------
extern "C" void kernel_launch(void* const* d_in, const int* in_sizes, int n_in,
                              void* d_out, int out_size, void* d_ws, size_t ws_size,
                              hipStream_t stream) {
    const float* querys = (const float*)d_in[0];
    const float* keys   = (const float*)d_in[1];
    const float* Wq     = (const float*)d_in[3];
    const float* Wk     = (const float*)d_in[4];

    float* out = (float*)d_out;
    float* ws  = (float*)d_ws;

    float* Qt    = ws;                                   // 12*50*4096 f
    float* Kt    = Qt + (size_t)NBATCH * DH * T;         // 12*50*4096 f
    float* pamax = Kt + (size_t)NBATCH * DH * T;         // QC*12*4096 f
    float* rmax  = pamax + (size_t)QC * NBATCH * T;      // RQC*12*NCAND f
    unsigned short* Qb = (unsigned short*)(rmax + (size_t)RQC * NBATCH * NCAND + 8);
    Qb = (unsigned short*)(((uintptr_t)Qb + 15) & ~(uintptr_t)15);
    unsigned short* Kb  = Qb  + (size_t)NBATCH * T * 64; // 12*4096*64 ush
    unsigned short* Whs = Kb  + (size_t)NBATCH * T * 64; // 2*304*320 ush
    unsigned short* Wls = Whs + (size_t)2 * JP * KP;
    int* cand = (int*)(Wls + (size_t)2 * JP * KP);       // 12*NCAND
    // total ~34.7 MB

    splitw_kernel   <<<(2 * JP * KP + 255) / 256, 256, 0, stream>>>(Wq, Wk, Whs, Wls);
    proj_mfma_kernel<<<dim3(64, JP / 16, 2), 256, 0, stream>>>(querys, keys, Whs, Wls, Qt, Kt);
    convert_kernel  <<<dim3(16, NBATCH, 2), 256, 0, stream>>>(Qt, Kt, Qb, Kb);
    score_mfma_kernel<<<dim3(16, NBATCH, QC), 256, 0, stream>>>(Qb, Kb, pamax);
    cand_kernel     <<<NBATCH, 256, 0, stream>>>(pamax, cand);
    rescore_kernel  <<<dim3(NBATCH, RQC), 256, 0, stream>>>(Qt, Kt, cand, rmax);
    final_kernel    <<<NBATCH, 64, 0, stream>>>(rmax, cand, Kt, out);
}